// Round 15
// baseline (2565.962 us; speedup 1.0000x reference)
//
#include <hip/hip_runtime.h>
#include <stdint.h>

typedef __bf16 bf16x8 __attribute__((ext_vector_type(8)));
typedef float  f32x4  __attribute__((ext_vector_type(4)));
typedef unsigned int u32x4 __attribute__((ext_vector_type(4)));
typedef unsigned long long u64;

__device__ __forceinline__ uint16_t f2b(float f) {
  uint32_t u = __float_as_uint(f);
  return (uint16_t)((u + 0x7FFFu + ((u >> 16) & 1u)) >> 16);
}
__device__ __forceinline__ float b2f(uint16_t h) {
  return __uint_as_float(((uint32_t)h) << 16);
}
__device__ __forceinline__ uint4 pack8f(float4 a, float4 b) {
  uint4 r;
  r.x = (uint32_t)f2b(a.x) | ((uint32_t)f2b(a.y) << 16);
  r.y = (uint32_t)f2b(a.z) | ((uint32_t)f2b(a.w) << 16);
  r.z = (uint32_t)f2b(b.x) | ((uint32_t)f2b(b.y) << 16);
  r.w = (uint32_t)f2b(b.z) | ((uint32_t)f2b(b.w) << 16);
  return r;
}
__device__ __forceinline__ float fsig(float x) {
  return 1.f / (1.f + __expf(-x));
}
__device__ __forceinline__ float ftanh(float x) {
  return 1.f - 2.f / (1.f + __expf(2.f * x));
}
// async global->LDS, 16B per lane. LDS dest must be wave-uniform base + lane*16.
__device__ __forceinline__ void gload_lds16(const void* g, void* l) {
  __builtin_amdgcn_global_load_lds(
      (const __attribute__((address_space(1))) uint32_t*)g,
      (__attribute__((address_space(3))) uint32_t*)l, 16, 0, 0);
}

// -------------------------------------------------------------------------
// Dtype detector: if W_proj is bf16-packed, low 16 bits of each u32 word are a
// plausible N(0,0.02) bf16 sample (~99.6% in (1e-4,0.5)); if fp32, low bits are
// mantissa noise (~5% pass). flag=1 -> bf16 buffers, flag=0 -> fp32 buffers.
__global__ void detect_kernel(const uint32_t* __restrict__ wproj, int* flag) {
  __shared__ int cnt;
  if (threadIdx.x == 0) cnt = 0;
  __syncthreads();
  int local = 0;
  for (int i = threadIdx.x; i < 1024; i += 256) {
    float v = __uint_as_float((wproj[i] & 0xFFFFu) << 16);
    float av = fabsf(v);
    if (av > 1e-4f && av < 0.5f) local++;
  }
  atomicAdd(&cnt, local);
  __syncthreads();
  if (threadIdx.x == 0) flag[0] = (cnt > 512) ? 1 : 0;
}

// Convert n elements (n % 2048 == 0) to canonical bf16. One thread = 8 elems.
__global__ void convert_kernel(const void* __restrict__ src,
                               uint16_t* __restrict__ dst,
                               const int* __restrict__ flagp) {
  int i = blockIdx.x * 256 + threadIdx.x;
  if (*flagp) {
    ((uint4*)dst)[i] = ((const uint4*)src)[i];
  } else {
    const float* s = (const float*)src + (size_t)i * 8;
    ((uint4*)dst)[i] = pack8f(*(const float4*)s, *(const float4*)(s + 4));
  }
}

// enc chunk c -> encb[16,512,1024] bf16, t0-MAJOR: row m' = t0*512 + b.
// Same f2b rounding as in-loop pack8f -> bit-identical GEMM inputs.
__global__ void convA_kernel(const void* __restrict__ enc,
                             uint16_t* __restrict__ encb,
                             const int* __restrict__ flagp, int c0) {
  int i = blockIdx.x * 256 + threadIdx.x;  // 1,048,576 threads, 8 elems each
  int mp = i >> 7, ch = i & 127;
  int t0 = mp >> 9, b = mp & 511;
  size_t src = ((size_t)b * 80 + c0 + t0) * 1024 + (size_t)ch * 8;
  if (*flagp) {
    ((uint4*)encb)[i] = *(const uint4*)((const uint16_t*)enc + src);
  } else {
    const float* s = (const float*)enc + src;
    ((uint4*)encb)[i] = pack8f(*(const float4*)s, *(const float4*)(s + 4));
  }
}

// word[b,:] = embed_table[start_ids[b], :]  -> bf16 [512,512]
__global__ void word_kernel(const int* __restrict__ ids,
                            const void* __restrict__ embed,
                            uint16_t* __restrict__ word,
                            const int* __restrict__ flagp) {
  int c = blockIdx.x * 256 + threadIdx.x;  // 32768 chunks of 8 elems
  int b = c >> 6, off = c & 63;
  size_t row = (size_t)ids[b] * 512;
  if (*flagp) {
    ((uint4*)word)[c] = ((const uint4*)((const uint16_t*)embed + row))[off];
  } else {
    const float* s = (const float*)embed + row + (size_t)off * 8;
    ((uint4*)word)[c] = pack8f(*(const float4*)s, *(const float4*)(s + 4));
  }
}

// bias2[j] = b_ih[j] + b_hh[j] + sum_f b_proj[f] * W_ih[j,f]
// One j per wave (4 waves/WG, 512 WGs), shuffle-reduce across 64 lanes.
__global__ void bias2_kernel(const void* __restrict__ bih,
                             const void* __restrict__ bhh,
                             const void* __restrict__ bproj,
                             const uint16_t* __restrict__ Wihb,
                             float* __restrict__ bias2,
                             const int* __restrict__ flagp) {
  const int wid = threadIdx.x >> 6, lane = threadIdx.x & 63;
  const int j = blockIdx.x * 4 + wid;  // 0..2047
  const int fl = *flagp;
  uint4 wv = *(const uint4*)(Wihb + (size_t)j * 1024 + lane * 8);
  const uint16_t wh[8] = {
      (uint16_t)wv.x, (uint16_t)(wv.x >> 16), (uint16_t)wv.y, (uint16_t)(wv.y >> 16),
      (uint16_t)wv.z, (uint16_t)(wv.z >> 16), (uint16_t)wv.w, (uint16_t)(wv.w >> 16)};
  float bp[8];
  if (fl) {
    uint4 pv = *(const uint4*)((const uint16_t*)bproj + lane * 8);
    const uint16_t ph[8] = {
        (uint16_t)pv.x, (uint16_t)(pv.x >> 16), (uint16_t)pv.y, (uint16_t)(pv.y >> 16),
        (uint16_t)pv.z, (uint16_t)(pv.z >> 16), (uint16_t)pv.w, (uint16_t)(pv.w >> 16)};
#pragma unroll
    for (int e = 0; e < 8; e++) bp[e] = b2f(ph[e]);
  } else {
    float4 p0 = ((const float4*)bproj)[lane * 2];
    float4 p1 = ((const float4*)bproj)[lane * 2 + 1];
    bp[0] = p0.x; bp[1] = p0.y; bp[2] = p0.z; bp[3] = p0.w;
    bp[4] = p1.x; bp[5] = p1.y; bp[6] = p1.z; bp[7] = p1.w;
  }
  float acc = 0.f;
#pragma unroll
  for (int e = 0; e < 8; e++) acc += bp[e] * b2f(wh[e]);
#pragma unroll
  for (int m = 32; m >= 1; m >>= 1) acc += __shfl_xor(acc, m, 64);
  if (lane == 0) {
    float s;
    if (fl) s = b2f(((const uint16_t*)bih)[j]) + b2f(((const uint16_t*)bhh)[j]);
    else    s = ((const float*)bih)[j] + ((const float*)bhh)[j];
    bias2[j] = s + acc;
  }
}

// -------------------------------------------------------------------------
// Setup GEMM: C[M,N] = A[M,K] @ Bt[N,K]^T, 128x128 tile, BK=32, gload staging.
// MODE 0: C bf16 row-major (ldc).  MODE 2: C fp32 (ldc), += wg[col].
template <int MODE>
__global__ __launch_bounds__(256, 2)
void gemm_bt(const uint16_t* __restrict__ A, int lda,
             const uint16_t* __restrict__ Bt, int ldb,
             void* __restrict__ Cout, int ldc, int K,
             const float* __restrict__ wg) {
  __shared__ __align__(16) uint16_t As[128 * 32];
  __shared__ __align__(16) uint16_t Bs[128 * 32];
  const int tid = threadIdx.x;
  const int bm = blockIdx.y * 128, bn = blockIdx.x * 128;
  const int wid = tid >> 6, lane = tid & 63;
  const int wm = (wid >> 1) * 64, wn = (wid & 1) * 64;
  const int lrow = lane & 15, quad = lane >> 4;
  const int srow = tid >> 2, scol = (tid & 3) * 8;

  const uint16_t* ga0 = A + (size_t)(bm + srow) * lda + scol;
  const uint16_t* ga1 = A + (size_t)(bm + 64 + srow) * lda + scol;
  const uint16_t* gb0 = Bt + (size_t)(bn + srow) * ldb + scol;
  const uint16_t* gb1 = Bt + (size_t)(bn + 64 + srow) * ldb + scol;
  uint16_t* la0 = As + srow * 32 + scol;
  uint16_t* la1 = As + (64 + srow) * 32 + scol;
  uint16_t* lb0 = Bs + srow * 32 + scol;
  uint16_t* lb1 = Bs + (64 + srow) * 32 + scol;

  f32x4 acc[4][4] = {};

  for (int kb = 0; kb < K; kb += 32) {
    __syncthreads();
    gload_lds16(ga0 + kb, la0);
    gload_lds16(ga1 + kb, la1);
    gload_lds16(gb0 + kb, lb0);
    gload_lds16(gb1 + kb, lb1);
    __syncthreads();
    bf16x8 af[4], bfr[4];
#pragma unroll
    for (int i = 0; i < 4; i++) {
      af[i]  = *reinterpret_cast<const bf16x8*>(As + (wm + i * 16 + lrow) * 32 + quad * 8);
      bfr[i] = *reinterpret_cast<const bf16x8*>(Bs + (wn + i * 16 + lrow) * 32 + quad * 8);
    }
#pragma unroll
    for (int i = 0; i < 4; i++)
#pragma unroll
      for (int j = 0; j < 4; j++)
        acc[i][j] = __builtin_amdgcn_mfma_f32_16x16x32_bf16(af[i], bfr[j], acc[i][j], 0, 0, 0);
  }

  if constexpr (MODE == 0) {
    uint16_t* C = (uint16_t*)Cout;
#pragma unroll
    for (int i = 0; i < 4; i++) {
      int row = bm + wm + i * 16 + quad * 4;
#pragma unroll
      for (int j = 0; j < 4; j++) {
        int col = bn + wn + j * 16 + lrow;
#pragma unroll
        for (int r = 0; r < 4; r++)
          C[(size_t)(row + r) * ldc + col] = f2b(acc[i][j][r]);
      }
    }
  } else {  // MODE 2
    float* C = (float*)Cout;
#pragma unroll
    for (int i = 0; i < 4; i++) {
      int row = bm + wm + i * 16 + quad * 4;
#pragma unroll
      for (int j = 0; j < 4; j++) {
        int col = bn + wn + j * 16 + lrow;
        float bias = wg[col];
#pragma unroll
        for (int r = 0; r < 4; r++)
          C[(size_t)(row + r) * ldc + col] = acc[i][j][r] + bias;
      }
    }
  }
}

// -------------------------------------------------------------------------
// Fused per-chunk cooperative kernel, 256 WGs x 512 threads (1 WG/CU).
// r13 POST-MORTEM: the 512-WG version's absmax (0.449 = max|ref|) was
// bit-identical across agent/system scope changes -> output was all zeros ->
// hipLaunchCooperativeKernel silently REJECTED the grid (occupancy calc with
// 49.7 KB LDS gives 1 WG/CU -> max 256 < 512). Fix: grid=256 (validates like
// the proven r7 launch) and split producer/consumer at the WAVE level:
//   waves 0..3 (tid 0..255): r7-proven LSTM consumer, formulas unchanged.
//   waves 4..7: xg producers -- LDS-free, barrier-free. Each wave computes
//     4 64x64x1024 tiles (global->VGPR fragments, no staging), system-scope
//     xg stores, s_waitcnt vmcnt(0) + relaxed system done[plane]++ (256/plane).
//     Round r covers planes 4r..4r+3 -> paced ahead of the consumer.
// Consumer waves replace __syncthreads (producers don't participate) with a
// 4-wave LDS barrier. r14 HARDENING: CONS_BAR executes an explicit
// s_waitcnt vmcnt(0) lgkmcnt(0) in ALL lanes before the arrive -- making it
// exactly __syncthreads-strength (drains each wave's global h/out stores)
// independent of how the LDS release-atomic is lowered.
// Cross-XCD xg path stays SYSTEM-scope (per-XCD L2s are not coherent);
// intra-XCD h-ring/cnt machinery stays agent/plain (r7-proven).
__global__ __launch_bounds__(512, 2)
void chunk_kernel(const uint16_t* __restrict__ Whhb,   // [2048,512] bf16
                  const uint16_t* __restrict__ encb,   // [16,512,1024] bf16
                  const uint16_t* __restrict__ combT,  // [2048,1024] bf16
                  const float* __restrict__ wgates,    // [512,2048] f32
                  float* __restrict__ xg,              // [16,512,2048] f32
                  uint16_t* __restrict__ hring,        // [17,512,512] bf16
                  float* __restrict__ cst,             // [512,512] f32
                  void* __restrict__ out,
                  int c,
                  const int* __restrict__ flagp,
                  unsigned int* __restrict__ bar) {
  __shared__ __align__(16) uint16_t Hs[32 * 512];  // 32 KB, XOR-swizzled rows
  __shared__ float Gs[4][32][33];                  // 16.9 KB gate staging
  __shared__ unsigned int cbar;                    // consumer-wave barrier
  const int tid = threadIdx.x;   // 0..511
  const int bid = blockIdx.x;    // 0..255
  const int wid = tid >> 6;      // 0..7
  const int lane = tid & 63;
  const int tbase = c * 16;
  unsigned int* done = bar + 1024;  // byte offset 4096 within bar region

  if (tid == 0) cbar = 0u;
  __syncthreads();  // the ONLY full-WG barrier; both halves execute it once

  if (wid >= 4) {
    // ------------------- producer: 4 waves, no LDS, no barriers -----------
    const int pw = bid * 4 + (wid - 4);  // 0..1023
    const int lrow = lane & 15, quad = lane >> 4;
#pragma unroll 1
    for (int r = 0; r < 4; r++) {
      const int t0 = r * 4 + (pw >> 8);           // planes 4r..4r+3 in round r
      const int q = pw & 255;
      const int b0 = (q & 7) * 64, j0 = (q >> 3) * 64;
      const uint16_t* Abase = encb + ((size_t)t0 * 512 + b0 + lrow) * 1024 + quad * 8;
      const uint16_t* Bbase = combT + ((size_t)(j0 + lrow)) * 1024 + quad * 8;
      f32x4 acc[4][4] = {};
      for (int kb = 0; kb < 1024; kb += 32) {
        bf16x8 af[4], bfr[4];
#pragma unroll
        for (int i = 0; i < 4; i++)
          af[i] = *reinterpret_cast<const bf16x8*>(Abase + (size_t)i * 16 * 1024 + kb);
#pragma unroll
        for (int j = 0; j < 4; j++)
          bfr[j] = *reinterpret_cast<const bf16x8*>(Bbase + (size_t)j * 16 * 1024 + kb);
#pragma unroll
        for (int i = 0; i < 4; i++)
#pragma unroll
          for (int j = 0; j < 4; j++)
            acc[i][j] = __builtin_amdgcn_mfma_f32_16x16x32_bf16(af[i], bfr[j], acc[i][j], 0, 0, 0);
      }
      // epilogue: xg[t0*512+b][col] = acc + wgates[b][col] (system stores)
#pragma unroll
      for (int i = 0; i < 4; i++)
#pragma unroll
        for (int rr = 0; rr < 4; rr++) {
          int b = b0 + i * 16 + quad * 4 + rr;
          float* crow = xg + ((size_t)t0 * 512 + b) * 2048;
          const float* wrow = wgates + (size_t)b * 2048;
#pragma unroll
          for (int j = 0; j < 4; j++) {
            int col = j0 + j * 16 + lrow;
            __hip_atomic_store(crow + col, acc[i][j][rr] + wrow[col],
                               __ATOMIC_RELAXED, __HIP_MEMORY_SCOPE_SYSTEM);
          }
        }
      asm volatile("s_waitcnt vmcnt(0)" ::: "memory");  // wave's stores done
      if (lane == 0)
        __hip_atomic_fetch_add(&done[tbase + t0], 1u, __ATOMIC_RELAXED,
                               __HIP_MEMORY_SCOPE_SYSTEM);
    }
    return;
  }

  // ---------------- consumer: 4 waves (tid 0..255), r7 structure ----------
  const int rb = ((bid & 7) << 1) | ((bid >> 3) & 1);  // 0..15
  const int cb = bid >> 4;                             // 0..15
  const int g = tid >> 6;                              // wave = gate (i,f,g,o)
  const int lrow = lane & 15, quad = lane >> 4;
  const int fl = *flagp;
  unsigned int btgt = 0;  // monotonic 4-wave barrier target

  // ---- Whh B-fragments for this wave's 32 gate-rows, all K, pinned ----
  u32x4 breg[2][16];
  {
    const uint16_t* wb = Whhb + ((size_t)(g * 512 + cb * 32 + lrow) * 512) + quad * 8;
#pragma unroll
    for (int j = 0; j < 2; j++)
#pragma unroll
      for (int kk = 0; kk < 16; kk++) {
        breg[j][kk] = *reinterpret_cast<const u32x4*>(wb + (size_t)j * 16 * 512 + kk * 32);
        asm volatile("" : "+v"(breg[j][kk]));  // force resident; block remat
      }
  }

  const int erow = tid >> 3;        // 0..31
  const int ecol = (tid & 7) * 4;   // 0..28
  const int gb = rb * 32 + erow;    // global batch row
  const int gh = cb * 32 + ecol;    // global h col
  f32x4 creg = *reinterpret_cast<const f32x4*>(cst + (size_t)gb * 512 + gh);

  const int sc16 = (tid & 7) * 16;  // staging byte-col base
  const int ssw = (erow & 7) << 4;  // staging row swizzle
  unsigned int* cnt = bar + rb * 64;  // 256 B apart per group

  // 4-wave barrier, __syncthreads-strength: all lanes drain vmcnt+lgkmcnt,
  // lane0 arrives (LDS add), all lanes acquire-spin until 4 arrivals.
#define CONS_BAR()                                                            \
  do {                                                                        \
    btgt += 4;                                                                \
    asm volatile("s_waitcnt vmcnt(0) lgkmcnt(0)" ::: "memory");               \
    if (lane == 0)                                                            \
      __hip_atomic_fetch_add(&cbar, 1u, __ATOMIC_RELEASE,                     \
                             __HIP_MEMORY_SCOPE_WORKGROUP);                   \
    while (__hip_atomic_load(&cbar, __ATOMIC_ACQUIRE,                         \
                             __HIP_MEMORY_SCOPE_WORKGROUP) < btgt)            \
      __builtin_amdgcn_s_sleep(1);                                            \
  } while (0)

#pragma unroll 1
  for (int s = 0; s < 16; s++) {
    const int t = tbase + s;
    const uint16_t* hin = hring + (size_t)((t + 16) % 17) * 262144;  // h(t-1)
    uint16_t* hout = hring + (size_t)(t % 17) * 262144;              // h(t)

    if (s == 0) {  // wait for this chunk's first xg plane (256 tiles)
      if (tid == 0)
        while (__hip_atomic_load(&done[t], __ATOMIC_RELAXED,
                                 __HIP_MEMORY_SCOPE_SYSTEM) < 256u)
          __builtin_amdgcn_s_sleep(1);
      CONS_BAR();
    }

    // xg loads: SYSTEM-scope relaxed (cross-XCD producers). Latency hidden
    // under h-stage + GEMM.
    const u64* xq = (const u64*)(xg + ((size_t)s * 512 + gb) * 2048 + gh);
    u64 q0 = __hip_atomic_load(xq + 0,   __ATOMIC_RELAXED, __HIP_MEMORY_SCOPE_SYSTEM);
    u64 q1 = __hip_atomic_load(xq + 1,   __ATOMIC_RELAXED, __HIP_MEMORY_SCOPE_SYSTEM);
    u64 q2 = __hip_atomic_load(xq + 256, __ATOMIC_RELAXED, __HIP_MEMORY_SCOPE_SYSTEM);
    u64 q3 = __hip_atomic_load(xq + 257, __ATOMIC_RELAXED, __HIP_MEMORY_SCOPE_SYSTEM);
    u64 q4 = __hip_atomic_load(xq + 512, __ATOMIC_RELAXED, __HIP_MEMORY_SCOPE_SYSTEM);
    u64 q5 = __hip_atomic_load(xq + 513, __ATOMIC_RELAXED, __HIP_MEMORY_SCOPE_SYSTEM);
    u64 q6 = __hip_atomic_load(xq + 768, __ATOMIC_RELAXED, __HIP_MEMORY_SCOPE_SYSTEM);
    u64 q7 = __hip_atomic_load(xq + 769, __ATOMIC_RELAXED, __HIP_MEMORY_SCOPE_SYSTEM);

    // stage h(t-1)[rb rows, all 512 cols] into LDS, swizzled (plain loads --
    // intra-XCD h-group, proven r7 pattern)
    {
      const char* hsrc = (const char*)(hin + (size_t)gb * 512);
      char* hdst = (char*)Hs + erow * 1024;
#pragma unroll
      for (int it = 0; it < 8; it++) {
        int bc = sc16 + it * 128;
        *reinterpret_cast<uint4*>(hdst + (bc ^ ssw)) =
            *reinterpret_cast<const uint4*>(hsrc + bc);
      }
    }
    CONS_BAR();

    // GEMM: gate-g preacts [32 x 32], K=512 from registers(B) x LDS(A)
    f32x4 acc[2][2] = {};
#pragma unroll
    for (int kk = 0; kk < 16; kk++) {
      bf16x8 af[2];
#pragma unroll
      for (int i = 0; i < 2; i++) {
        int r = i * 16 + lrow;
        int bc = kk * 64 + quad * 16;
        af[i] = *reinterpret_cast<const bf16x8*>(
            (const char*)Hs + r * 1024 + (bc ^ ((r & 7) << 4)));
      }
#pragma unroll
      for (int i = 0; i < 2; i++)
#pragma unroll
        for (int j = 0; j < 2; j++)
          acc[i][j] = __builtin_amdgcn_mfma_f32_16x16x32_bf16(
              af[i], __builtin_bit_cast(bf16x8, breg[j][kk]), acc[i][j], 0, 0, 0);
    }

#pragma unroll
    for (int i = 0; i < 2; i++)
#pragma unroll
      for (int j = 0; j < 2; j++)
#pragma unroll
        for (int r = 0; r < 4; r++)
          Gs[g][i * 16 + quad * 4 + r][j * 16 + lrow] = acc[i][j][r];
    CONS_BAR();

    // epilogue: 4 outputs/thread, c in registers
    f32x4 x0, x1, x2, x3;
    { float2 a = __builtin_bit_cast(float2, q0), b = __builtin_bit_cast(float2, q1);
      x0[0] = a.x; x0[1] = a.y; x0[2] = b.x; x0[3] = b.y; }
    { float2 a = __builtin_bit_cast(float2, q2), b = __builtin_bit_cast(float2, q3);
      x1[0] = a.x; x1[1] = a.y; x1[2] = b.x; x1[3] = b.y; }
    { float2 a = __builtin_bit_cast(float2, q4), b = __builtin_bit_cast(float2, q5);
      x2[0] = a.x; x2[1] = a.y; x2[2] = b.x; x2[3] = b.y; }
    { float2 a = __builtin_bit_cast(float2, q6), b = __builtin_bit_cast(float2, q7);
      x3[0] = a.x; x3[1] = a.y; x3[2] = b.x; x3[3] = b.y; }
    float hnv[4];
#pragma unroll
    for (int e = 0; e < 4; e++) {
      float p_i = Gs[0][erow][ecol + e] + x0[e];
      float p_f = Gs[1][erow][ecol + e] + x1[e];
      float p_g = Gs[2][erow][ecol + e] + x2[e];
      float p_o = Gs[3][erow][ecol + e] + x3[e];
      float si = fsig(p_i);
      float sf = fsig(p_f);
      float so = fsig(p_o);
      float tg = ftanh(p_g);
      float cn = sf * creg[e] + si * tg;
      creg[e] = cn;
      hnv[e] = so * ftanh(cn);
    }
    uint2 hp;
    hp.x = (uint32_t)f2b(hnv[0]) | ((uint32_t)f2b(hnv[1]) << 16);
    hp.y = (uint32_t)f2b(hnv[2]) | ((uint32_t)f2b(hnv[3]) << 16);
    // h store: agent-relaxed (intra-XCD group, r7-proven), no fence
    u64 hv = (u64)hp.x | ((u64)hp.y << 32);
    __hip_atomic_store((u64*)(hout + (size_t)gb * 512 + gh), hv,
                       __ATOMIC_RELAXED, __HIP_MEMORY_SCOPE_AGENT);
    size_t oi = (size_t)gb * (80 * 512) + (size_t)t * 512 + gh;
    if (fl) {
      *reinterpret_cast<uint2*>((uint16_t*)out + oi) = hp;
    } else {
      float4 ov = make_float4(hnv[0], hnv[1], hnv[2], hnv[3]);
      *reinterpret_cast<float4*>((float*)out + oi) = ov;
    }

    // group barrier: CONS_BAR drains every consumer wave's vmcnt (h stores
    // at the coherence point), then one relaxed atomic arrive + poll
    // (h-group agent AND next xg plane system).
    CONS_BAR();
    if (tid == 0) {
      __hip_atomic_fetch_add(cnt, 1u, __ATOMIC_RELAXED, __HIP_MEMORY_SCOPE_AGENT);
      if (s != 15) {
        unsigned tgt = (unsigned)(t + 1) * 16u;
        while (__hip_atomic_load(cnt, __ATOMIC_RELAXED, __HIP_MEMORY_SCOPE_AGENT) < tgt ||
               __hip_atomic_load(&done[t + 1], __ATOMIC_RELAXED,
                                 __HIP_MEMORY_SCOPE_SYSTEM) < 256u)
          __builtin_amdgcn_s_sleep(1);
      }
    }
    CONS_BAR();
  }
#undef CONS_BAR

  *reinterpret_cast<f32x4*>(cst + (size_t)gb * 512 + gh) = creg;
}

// -------------------------------------------------------------------------
extern "C" void kernel_launch(void* const* d_in, const int* in_sizes, int n_in,
                              void* d_out, int out_size, void* d_ws, size_t ws_size,
                              hipStream_t stream) {
  const void* enc   = d_in[0];            // [512,80,1024]
  const int*  ids   = (const int*)d_in[1];
  const void* Wproj = d_in[2];            // [1024,512]
  const void* bproj = d_in[3];
  const void* embed = d_in[4];            // [10000,512]
  const void* Wih   = d_in[5];            // [2048,1024]
  const void* Whh   = d_in[6];            // [2048,512]
  const void* bih   = d_in[7];
  const void* bhh   = d_in[8];

  uint8_t* w = (uint8_t*)d_ws;
  int*      flag   = (int*)w;                    // 16 KB reserved
  unsigned int* bar = (unsigned int*)(w + 8192); // 8 KB: h counters + done[]
  float*    bias2  = (float*)(w + 16384);        // 8 KB
  float*    wgates = (float*)(w + 32768);        // [512,2048] f32, 4 MB
  uint16_t* combT  = (uint16_t*)(w + 4227072);   // [2048,1024] bf16, 4 MB
  uint16_t* Wihb   = (uint16_t*)(w + 8421376);   // [2048,1024] bf16, 4 MB
  uint16_t* Whhb   = (uint16_t*)(w + 12615680);  // [2048,512] bf16, 2 MB
  uint16_t* Wprojb = (uint16_t*)(w + 14712832);  // [1024,512] bf16, 1 MB
  uint16_t* word   = (uint16_t*)(w + 15761408);  // [512,512] bf16, 512 KB
  float*    cst    = (float*)(w + 17334272);     // [512,512] f32, 1 MB
  float*    xgbuf  = (float*)(w + 18382848);     // [16,512,2048] f32, 64 MB
  uint16_t* hring  = (uint16_t*)(w + 85491712);  // [17,512,512] bf16, 8.9 MB
  uint16_t* encb   = (uint16_t*)(w + 94404608);  // [16,512,1024] bf16, 16.8 MB

  detect_kernel<<<1, 256, 0, stream>>>((const uint32_t*)Wproj, flag);
  convert_kernel<<<1024, 256, 0, stream>>>(Wih, Wihb, flag);     // 2M elems
  convert_kernel<<<512, 256, 0, stream>>>(Whh, Whhb, flag);      // 1M
  convert_kernel<<<256, 256, 0, stream>>>(Wproj, Wprojb, flag);  // 512K
  word_kernel<<<128, 256, 0, stream>>>(ids, embed, word, flag);
  bias2_kernel<<<512, 256, 0, stream>>>(bih, bhh, bproj, Wihb, bias2, flag);

  // combT[j,d] = sum_f W_ih[j,f] * W_proj[d,f]   (M=2048,N=1024,K=512)
  gemm_bt<0><<<dim3(8, 16), 256, 0, stream>>>(Wihb, 1024, Wprojb, 512,
                                              combT, 1024, 512, nullptr);
  // wgates[b,j] = sum_w word[b,w]*W_ih[j,512+w] + bias2[j]  (M=512,N=2048,K=512)
  gemm_bt<2><<<dim3(16, 4), 256, 0, stream>>>(word, 512, Wihb + 512, 1024,
                                              wgates, 2048, 512, bias2);

  (void)hipMemsetAsync(hring + (size_t)16 * 262144, 0, 524288, stream);  // h(-1)=0
  (void)hipMemsetAsync(cst, 0, 512 * 512 * 4, stream);
  (void)hipMemsetAsync(bar, 0, 8192, stream);  // h counters + done[]

  const uint16_t* Whhb_a = Whhb;
  const uint16_t* encb_a = encb;
  const uint16_t* combT_a = combT;
  const float* wgates_a = wgates;
  float* xg_a = xgbuf;
  uint16_t* hring_a = hring;
  float* cst_a = cst;
  void* out_a = d_out;
  const int* flag_a = flag;
  unsigned int* bar_a = bar;

  for (int c = 0; c < 5; c++) {
    // encb[t0*512+b, d] = bf16(enc[b, c*16+t0, d])  (t0-major for fixed-t0 tiles)
    convA_kernel<<<4096, 256, 0, stream>>>(enc, encb, flag, c * 16);
    int cc = c;
    void* kargs[] = {(void*)&Whhb_a, (void*)&encb_a, (void*)&combT_a,
                     (void*)&wgates_a, (void*)&xg_a, (void*)&hring_a,
                     (void*)&cst_a, (void*)&out_a, (void*)&cc,
                     (void*)&flag_a, (void*)&bar_a};
    (void)hipLaunchCooperativeKernel(chunk_kernel, dim3(256), dim3(512), kargs,
                                     0u, stream);
  }
}